// Round 1
// baseline (1570.656 us; speedup 1.0000x reference)
//
#include <hip/hip_runtime.h>
#include <math.h>

#define NN 100000
#define NE 1600000

// ---------------------------------------------------------------------------
// Generic tiled fp32 GEMM: Y[M,N] = X[M,K] @ W[K,N], N <= 64, K % 32 == 0.
// 64-row x 64-col tile per block, 256 threads, 4x4 register micro-tile.
// W cols >= N are zero-padded in LDS so one kernel serves N=64 and N=40.
// ---------------------------------------------------------------------------
template <int K>
__global__ __launch_bounds__(256) void gemm_kernel(
    const float* __restrict__ X, const float* __restrict__ W,
    float* __restrict__ Y, int M, int N) {
  __shared__ float xs[32][68];   // [kk][row]  (transposed for float4 reads)
  __shared__ float wsh[32][68];  // [kk][col]
  const int tid = threadIdx.x;
  const int row0 = blockIdx.x * 64;
  const int tc = (tid & 15) * 4;  // 4 cols
  const int tr = (tid >> 4) * 4;  // 4 rows
  float acc[4][4];
#pragma unroll
  for (int i = 0; i < 4; i++)
#pragma unroll
    for (int j = 0; j < 4; j++) acc[i][j] = 0.f;

  for (int k0 = 0; k0 < K; k0 += 32) {
    // stage X^T: 64 rows x 32 k values
#pragma unroll
    for (int i = tid; i < 64 * 32; i += 256) {
      int r = i >> 5, c = i & 31;
      int row = row0 + r;
      xs[c][r] = (row < M) ? X[(long)row * K + k0 + c] : 0.f;
    }
    // stage W: 32 k x 64 cols (pad cols >= N with 0)
#pragma unroll
    for (int i = tid; i < 32 * 64; i += 256) {
      int r = i >> 6, c = i & 63;
      wsh[r][c] = (c < N) ? W[(long)(k0 + r) * N + c] : 0.f;
    }
    __syncthreads();
#pragma unroll
    for (int kk = 0; kk < 32; ++kk) {
      float4 xv = *(const float4*)&xs[kk][tr];
      float4 wv = *(const float4*)&wsh[kk][tc];
      float xa[4] = {xv.x, xv.y, xv.z, xv.w};
      float wa[4] = {wv.x, wv.y, wv.z, wv.w};
#pragma unroll
      for (int i = 0; i < 4; i++)
#pragma unroll
        for (int j = 0; j < 4; j++) acc[i][j] += xa[i] * wa[j];
    }
    __syncthreads();
  }
#pragma unroll
  for (int i = 0; i < 4; i++) {
    int row = row0 + tr + i;
    if (row < M) {
#pragma unroll
      for (int j = 0; j < 4; j++) {
        int col = tc + j;
        if (col < N) Y[(long)row * N + col] = acc[i][j];
      }
    }
  }
}

// ---------------------------------------------------------------------------
// Edge scatter: one wave per edge, lane = feature dim.
// out[dst[e]][d] += w[e] * H[src[e]][d]   (fp32 HW atomic)
// ---------------------------------------------------------------------------
template <int D>
__global__ __launch_bounds__(256) void scatter_kernel(
    const int* __restrict__ src, const int* __restrict__ dst,
    const float* __restrict__ ew, const float* __restrict__ H,
    float* __restrict__ out, int nE) {
  int lane = threadIdx.x & 63;
  int e = blockIdx.x * 4 + (threadIdx.x >> 6);
  if (e >= nE) return;
  int s = src[e];
  int d = dst[e];
  float w = ew[e];
  if (lane < D) {
    float v = H[(long)s * D + lane] * w;
    unsafeAtomicAdd(&out[(long)d * D + lane], v);
  }
}

// ---------------------------------------------------------------------------
// out[i] = relu(in[i] + b[i % 64])
// ---------------------------------------------------------------------------
__global__ __launch_bounds__(256) void bias_relu_kernel(
    const float* __restrict__ in, const float* __restrict__ b,
    float* __restrict__ out, int n) {
  int i = blockIdx.x * 256 + threadIdx.x;
  if (i < n) {
    float v = in[i] + b[i & 63];
    out[i] = v > 0.f ? v : 0.f;
  }
}

// ---------------------------------------------------------------------------
// Row-wise log_softmax over 40 cols, one wave per row (lanes >= 40 idle).
// out[r][c] = v - max - log(sum(exp(v - max))),  v = in[r][c] + b[c]
// ---------------------------------------------------------------------------
__global__ __launch_bounds__(256) void logsoftmax_kernel(
    const float* __restrict__ in, const float* __restrict__ b,
    float* __restrict__ out, int M) {
  int lane = threadIdx.x & 63;
  int row = blockIdx.x * 4 + (threadIdx.x >> 6);
  if (row >= M) return;
  float v = (lane < 40) ? in[(long)row * 40 + lane] + b[lane] : -INFINITY;
  float m = v;
#pragma unroll
  for (int off = 32; off > 0; off >>= 1) m = fmaxf(m, __shfl_xor(m, off, 64));
  float e = (lane < 40) ? __expf(v - m) : 0.f;
  float s = e;
#pragma unroll
  for (int off = 32; off > 0; off >>= 1) s += __shfl_xor(s, off, 64);
  if (lane < 40) out[(long)row * 40 + lane] = v - m - __logf(s);
}

extern "C" void kernel_launch(void* const* d_in, const int* in_sizes, int n_in,
                              void* d_out, int out_size, void* d_ws,
                              size_t ws_size, hipStream_t stream) {
  const int* edge_index = (const int*)d_in[0];
  const float* features = (const float*)d_in[1];
  const float* ew = (const float*)d_in[2];
  const float* W1 = (const float*)d_in[3];
  const float* b1 = (const float*)d_in[4];
  const float* W2 = (const float*)d_in[5];
  const float* b2 = (const float*)d_in[6];
  const float* W3 = (const float*)d_in[7];
  const float* b3 = (const float*)d_in[8];
  float* out = (float*)d_out;
  const int* src = edge_index;       // row 0
  const int* dst = edge_index + NE;  // row 1

  float* bufA = (float*)d_ws;                // NN*64 floats
  float* bufB = bufA + (size_t)NN * 64;      // NN*64 floats

  dim3 blk(256);
  const int gemm_grid = (NN + 63) / 64;      // 1563
  const int sc_grid = (NE + 3) / 4;          // 400000
  const int ew_grid = (NN * 64 + 255) / 256; // 25000

  // ---- layer 1: h1 = feat @ W1 ; agg ; relu(+b1) ----
  gemm_kernel<512><<<gemm_grid, blk, 0, stream>>>(features, W1, bufA, NN, 64);
  hipMemsetAsync(bufB, 0, (size_t)NN * 64 * sizeof(float), stream);
  scatter_kernel<64><<<sc_grid, blk, 0, stream>>>(src, dst, ew, bufA, bufB, NE);
  bias_relu_kernel<<<ew_grid, blk, 0, stream>>>(bufB, b1, bufA, NN * 64);

  // ---- layer 2: h2 = x2 @ W2 ; agg ; relu(+b2) ----
  gemm_kernel<64><<<gemm_grid, blk, 0, stream>>>(bufA, W2, bufB, NN, 64);
  hipMemsetAsync(bufA, 0, (size_t)NN * 64 * sizeof(float), stream);
  scatter_kernel<64><<<sc_grid, blk, 0, stream>>>(src, dst, ew, bufB, bufA, NE);
  bias_relu_kernel<<<ew_grid, blk, 0, stream>>>(bufA, b2, bufB, NN * 64);

  // ---- layer 3: h3 = x3 @ W3 ; agg ; log_softmax(+b3) ----
  gemm_kernel<64><<<gemm_grid, blk, 0, stream>>>(bufB, W3, bufA, NN, 40);
  hipMemsetAsync(bufB, 0, (size_t)NN * 40 * sizeof(float), stream);
  scatter_kernel<40><<<sc_grid, blk, 0, stream>>>(src, dst, ew, bufA, bufB, NE);
  logsoftmax_kernel<<<(NN + 3) / 4, blk, 0, stream>>>(bufB, b3, out, NN);
}

// Round 2
// 1193.704 us; speedup vs baseline: 1.3158x; 1.3158x over previous
//
#include <hip/hip_runtime.h>
#include <math.h>

#define NN 100000
#define NE 1600000
#define NB_SCAN ((NN + 255) / 256)  // 391

// ---------------------------------------------------------------------------
// Generic tiled fp32 GEMM: Y[M,N] = X[M,K] @ W[K,N], N <= 64, K % 32 == 0.
// ---------------------------------------------------------------------------
template <int K>
__global__ __launch_bounds__(256) void gemm_kernel(
    const float* __restrict__ X, const float* __restrict__ W,
    float* __restrict__ Y, int M, int N) {
  __shared__ float xs[32][68];   // [kk][row]
  __shared__ float wsh[32][68];  // [kk][col]
  const int tid = threadIdx.x;
  const int row0 = blockIdx.x * 64;
  const int tc = (tid & 15) * 4;
  const int tr = (tid >> 4) * 4;
  float acc[4][4];
#pragma unroll
  for (int i = 0; i < 4; i++)
#pragma unroll
    for (int j = 0; j < 4; j++) acc[i][j] = 0.f;

  for (int k0 = 0; k0 < K; k0 += 32) {
#pragma unroll
    for (int i = tid; i < 64 * 32; i += 256) {
      int r = i >> 5, c = i & 31;
      int row = row0 + r;
      xs[c][r] = (row < M) ? X[(long)row * K + k0 + c] : 0.f;
    }
#pragma unroll
    for (int i = tid; i < 32 * 64; i += 256) {
      int r = i >> 6, c = i & 63;
      wsh[r][c] = (c < N) ? W[(long)(k0 + r) * N + c] : 0.f;
    }
    __syncthreads();
#pragma unroll
    for (int kk = 0; kk < 32; ++kk) {
      float4 xv = *(const float4*)&xs[kk][tr];
      float4 wv = *(const float4*)&wsh[kk][tc];
      float xa[4] = {xv.x, xv.y, xv.z, xv.w};
      float wa[4] = {wv.x, wv.y, wv.z, wv.w};
#pragma unroll
      for (int i = 0; i < 4; i++)
#pragma unroll
        for (int j = 0; j < 4; j++) acc[i][j] += xa[i] * wa[j];
    }
    __syncthreads();
  }
#pragma unroll
  for (int i = 0; i < 4; i++) {
    int row = row0 + tr + i;
    if (row < M) {
#pragma unroll
      for (int j = 0; j < 4; j++) {
        int col = tc + j;
        if (col < N) Y[(long)row * N + col] = acc[i][j];
      }
    }
  }
}

// ---------------------------------------------------------------------------
// CSR build: histogram -> 3-phase exclusive scan -> fill (src,w) pairs
// ---------------------------------------------------------------------------
__global__ __launch_bounds__(256) void hist_kernel(const int* __restrict__ dst,
                                                   int* __restrict__ deg, int n) {
  int e = blockIdx.x * 256 + threadIdx.x;
  if (e < n) atomicAdd(&deg[dst[e]], 1);
}

__global__ __launch_bounds__(256) void scan_blocks_kernel(
    const int* __restrict__ deg, int* __restrict__ rowptr,
    int* __restrict__ partials, int n) {
  __shared__ int tmp[256];
  int tid = threadIdx.x;
  int gid = blockIdx.x * 256 + tid;
  int v = (gid < n) ? deg[gid] : 0;
  tmp[tid] = v;
  __syncthreads();
#pragma unroll
  for (int off = 1; off < 256; off <<= 1) {
    int t = (tid >= off) ? tmp[tid - off] : 0;
    __syncthreads();
    tmp[tid] += t;
    __syncthreads();
  }
  if (gid < n) rowptr[gid] = tmp[tid] - v;  // exclusive
  if (tid == 255) partials[blockIdx.x] = tmp[255];
}

__global__ __launch_bounds__(64) void scan_partials_kernel(int* __restrict__ p,
                                                           int n) {
  int lane = threadIdx.x;
  int carry = 0;
  for (int base = 0; base < n; base += 64) {
    int i = base + lane;
    int v = (i < n) ? p[i] : 0;
#pragma unroll
    for (int off = 1; off < 64; off <<= 1) {
      int t = __shfl_up(v, off, 64);
      if (lane >= off) v += t;
    }
    int total = __shfl(v, 63, 64);
    int ex = __shfl_up(v, 1, 64);
    if (lane == 0) ex = 0;
    if (i < n) p[i] = carry + ex;
    carry += total;
  }
}

__global__ __launch_bounds__(256) void add_offsets_kernel(
    int* __restrict__ rowptr, int* __restrict__ cursor,
    const int* __restrict__ partials, int n) {
  int gid = blockIdx.x * 256 + threadIdx.x;
  if (gid < n) {
    int v = rowptr[gid] + partials[blockIdx.x];
    rowptr[gid] = v;
    cursor[gid] = v;
  }
}

__global__ __launch_bounds__(256) void fill_kernel(
    const int* __restrict__ src, const int* __restrict__ dst,
    const float* __restrict__ ew, int* __restrict__ cursor,
    int2* __restrict__ csr, int n) {
  int e = blockIdx.x * 256 + threadIdx.x;
  if (e < n) {
    int d = dst[e];
    int pos = atomicAdd(&cursor[d], 1);
    csr[pos] = make_int2(src[e], __float_as_int(ew[e]));
  }
}

// ---------------------------------------------------------------------------
// Pull aggregation: one wave per dst row, lane = dim.
// out[r][lane] = relu?( sum_j w_j * H[src_j][lane] + b[lane] )
// ---------------------------------------------------------------------------
template <int D, bool RELU>
__global__ __launch_bounds__(256) void agg_kernel(
    const int* __restrict__ rowptr, const int* __restrict__ deg,
    const int2* __restrict__ csr, const float* __restrict__ H,
    const float* __restrict__ b, float* __restrict__ out, int nR) {
  int lane = threadIdx.x & 63;
  int r = blockIdx.x * 4 + (threadIdx.x >> 6);
  if (r >= nR) return;
  int beg = rowptr[r];
  int d = deg[r];
  float acc = 0.f;
  for (int j = 0; j < d; ++j) {
    int2 cw = csr[beg + j];
    float w = __int_as_float(cw.y);
    if (D == 64 || lane < D) acc += w * H[(long)cw.x * D + lane];
  }
  if (lane < D) {
    float v = acc + b[lane];
    if (RELU) v = v > 0.f ? v : 0.f;
    out[(long)r * D + lane] = v;
  }
}

// ---------------------------------------------------------------------------
// Layer-3 fused: aggregation (D=40) + bias + log_softmax, one wave per row.
// ---------------------------------------------------------------------------
__global__ __launch_bounds__(256) void agg_lsm_kernel(
    const int* __restrict__ rowptr, const int* __restrict__ deg,
    const int2* __restrict__ csr, const float* __restrict__ H,
    const float* __restrict__ b, float* __restrict__ out, int nR) {
  int lane = threadIdx.x & 63;
  int r = blockIdx.x * 4 + (threadIdx.x >> 6);
  if (r >= nR) return;
  int beg = rowptr[r];
  int d = deg[r];
  float acc = 0.f;
  for (int j = 0; j < d; ++j) {
    int2 cw = csr[beg + j];
    float w = __int_as_float(cw.y);
    if (lane < 40) acc += w * H[(long)cw.x * 40 + lane];
  }
  float v = (lane < 40) ? acc + b[lane] : -INFINITY;
  float m = v;
#pragma unroll
  for (int off = 32; off > 0; off >>= 1) m = fmaxf(m, __shfl_xor(m, off, 64));
  float e = (lane < 40) ? __expf(v - m) : 0.f;
  float s = e;
#pragma unroll
  for (int off = 32; off > 0; off >>= 1) s += __shfl_xor(s, off, 64);
  if (lane < 40) out[(long)r * 40 + lane] = v - m - __logf(s);
}

extern "C" void kernel_launch(void* const* d_in, const int* in_sizes, int n_in,
                              void* d_out, int out_size, void* d_ws,
                              size_t ws_size, hipStream_t stream) {
  const int* edge_index = (const int*)d_in[0];
  const float* features = (const float*)d_in[1];
  const float* ew = (const float*)d_in[2];
  const float* W1 = (const float*)d_in[3];
  const float* b1 = (const float*)d_in[4];
  const float* W2 = (const float*)d_in[5];
  const float* b2 = (const float*)d_in[6];
  const float* W3 = (const float*)d_in[7];
  const float* b3 = (const float*)d_in[8];
  float* out = (float*)d_out;
  const int* src = edge_index;
  const int* dst = edge_index + NE;

  // workspace layout (all 4B elems; int2 region 8B-aligned by construction)
  float* bufA = (float*)d_ws;                  // NN*64
  float* bufB = bufA + (size_t)NN * 64;        // NN*64
  int* deg = (int*)(bufB + (size_t)NN * 64);   // NN
  int* rowptr = deg + NN;                      // NN
  int* cursor = rowptr + NN;                   // NN
  int* partials = cursor + NN;                 // 1024
  int2* csr = (int2*)(partials + 1024);        // NE

  dim3 blk(256);
  const int gemm_grid = (NN + 63) / 64;
  const int edge_grid = (NE + 255) / 256;
  const int row_grid = (NN + 3) / 4;

  // ---- CSR build (by dst) ----
  hipMemsetAsync(deg, 0, NN * sizeof(int), stream);
  hist_kernel<<<edge_grid, blk, 0, stream>>>(dst, deg, NE);
  scan_blocks_kernel<<<NB_SCAN, blk, 0, stream>>>(deg, rowptr, partials, NN);
  scan_partials_kernel<<<1, 64, 0, stream>>>(partials, NB_SCAN);
  add_offsets_kernel<<<NB_SCAN, blk, 0, stream>>>(rowptr, cursor, partials, NN);
  fill_kernel<<<edge_grid, blk, 0, stream>>>(src, dst, ew, cursor, csr, NE);

  // ---- layer 1 ----
  gemm_kernel<512><<<gemm_grid, blk, 0, stream>>>(features, W1, bufA, NN, 64);
  agg_kernel<64, true><<<row_grid, blk, 0, stream>>>(rowptr, deg, csr, bufA, b1,
                                                     bufB, NN);
  // ---- layer 2 ----
  gemm_kernel<64><<<gemm_grid, blk, 0, stream>>>(bufB, W2, bufA, NN, 64);
  agg_kernel<64, true><<<row_grid, blk, 0, stream>>>(rowptr, deg, csr, bufA, b2,
                                                     bufB, NN);
  // ---- layer 3 ----
  gemm_kernel<64><<<gemm_grid, blk, 0, stream>>>(bufB, W3, bufA, NN, 40);
  agg_lsm_kernel<<<row_grid, blk, 0, stream>>>(rowptr, deg, csr, bufA, b3, out,
                                               NN);
}

// Round 3
// 983.923 us; speedup vs baseline: 1.5963x; 1.2132x over previous
//
#include <hip/hip_runtime.h>
#include <hip/hip_bf16.h>
#include <math.h>

#define NN 100000
#define NE 1600000
#define NB_SCAN ((NN + 255) / 256)  // 391

typedef __attribute__((ext_vector_type(8))) short bf8_t;   // 8 bf16 = 4 VGPRs
typedef __attribute__((ext_vector_type(4))) float f4_t;    // 4 fp32 acc

__device__ __forceinline__ ushort f2b(float f) {
  __hip_bfloat16 h = __float2bfloat16(f);  // RNE
  return *(ushort*)&h;
}
__device__ __forceinline__ float b2f(ushort u) {
  return __uint_as_float(((unsigned)u) << 16);
}

// ---------------------------------------------------------------------------
// bf16 MFMA GEMM: Y[M,N] = X[M,K] @ W[K,N] (bf16 out, fp32 W staged in-kernel)
// X is fp32 (XF32=true, layer 1) or bf16 (layers 2/3).
// Tile: 64 rows x 64 cols, 4 waves, wave = 16 rows x 64 cols via 4 MFMA accs.
// ---------------------------------------------------------------------------
template <int K, int N, bool XF32>
__global__ __launch_bounds__(256) void mfma_gemm(
    const void* __restrict__ Xv, const float* __restrict__ Wf,
    ushort* __restrict__ Y, int M) {
  __shared__ ushort xs[64][72];   // [row][k], stride 144B (16B-aligned rows)
  __shared__ ushort wsh[64][72];  // [n][k] transposed

  const int tid = threadIdx.x;
  const int wave = tid >> 6;
  const int lane = tid & 63;
  const int row0 = blockIdx.x * 64;

  f4_t acc[4];
#pragma unroll
  for (int t = 0; t < 4; t++) acc[t] = (f4_t){0.f, 0.f, 0.f, 0.f};

  for (int k0 = 0; k0 < K; k0 += 64) {
    // ---- stage X tile (64 rows x 64 k) as bf16 ----
#pragma unroll
    for (int i = 0; i < 4; i++) {
      int fidx = i * 256 + tid;
      int row = fidx >> 4;
      int kq = (fidx & 15) * 4;
      ushort4 uv = make_ushort4(0, 0, 0, 0);
      if (row0 + row < M) {
        if (XF32) {
          const float* Xf = (const float*)Xv;
          float4 xv = *(const float4*)&Xf[(long)(row0 + row) * K + k0 + kq];
          uv = make_ushort4(f2b(xv.x), f2b(xv.y), f2b(xv.z), f2b(xv.w));
        } else {
          const ushort* Xb = (const ushort*)Xv;
          uv = *(const ushort4*)&Xb[(long)(row0 + row) * K + k0 + kq];
        }
      }
      *(ushort4*)&xs[row][kq] = uv;
    }
    // ---- stage W tile (64 k x 64 n, transposed, cols >= N zero) ----
#pragma unroll
    for (int i = 0; i < 4; i++) {
      int widx = i * 256 + tid;
      int n = widx & 63;
      int kq = (widx >> 6) * 4;
      ushort4 uv = make_ushort4(0, 0, 0, 0);
      if (n < N) {
        uv.x = f2b(Wf[(long)(k0 + kq + 0) * N + n]);
        uv.y = f2b(Wf[(long)(k0 + kq + 1) * N + n]);
        uv.z = f2b(Wf[(long)(k0 + kq + 2) * N + n]);
        uv.w = f2b(Wf[(long)(k0 + kq + 3) * N + n]);
      }
      *(ushort4*)&wsh[n][kq] = uv;
    }
    __syncthreads();
    // ---- MFMA: 2 k-steps of 32 ----
#pragma unroll
    for (int s = 0; s < 2; s++) {
      bf8_t af = *(const bf8_t*)&xs[wave * 16 + (lane & 15)][s * 32 + (lane >> 4) * 8];
#pragma unroll
      for (int t = 0; t < 4; t++) {
        bf8_t bf = *(const bf8_t*)&wsh[t * 16 + (lane & 15)][s * 32 + (lane >> 4) * 8];
        acc[t] = __builtin_amdgcn_mfma_f32_16x16x32_bf16(af, bf, acc[t], 0, 0, 0);
      }
    }
    __syncthreads();
  }
  // ---- epilogue: C layout col=lane&15, row=(lane>>4)*4+reg ----
  const int crow0 = row0 + wave * 16 + (lane >> 4) * 4;
  const int ccol = lane & 15;
#pragma unroll
  for (int t = 0; t < 4; t++) {
    int col = ccol + t * 16;
    if (col < N) {
#pragma unroll
      for (int r = 0; r < 4; r++) {
        int row = crow0 + r;
        if (row < M) Y[(long)row * N + col] = f2b(acc[t][r]);
      }
    }
  }
}

// ---------------------------------------------------------------------------
// CSR build: histogram -> 3-phase exclusive scan -> fill (src,w) pairs
// ---------------------------------------------------------------------------
__global__ __launch_bounds__(256) void hist_kernel(const int* __restrict__ dst,
                                                   int* __restrict__ deg, int n) {
  int e = blockIdx.x * 256 + threadIdx.x;
  if (e < n) atomicAdd(&deg[dst[e]], 1);
}

__global__ __launch_bounds__(256) void scan_blocks_kernel(
    const int* __restrict__ deg, int* __restrict__ rowptr,
    int* __restrict__ partials, int n) {
  __shared__ int tmp[256];
  int tid = threadIdx.x;
  int gid = blockIdx.x * 256 + tid;
  int v = (gid < n) ? deg[gid] : 0;
  tmp[tid] = v;
  __syncthreads();
#pragma unroll
  for (int off = 1; off < 256; off <<= 1) {
    int t = (tid >= off) ? tmp[tid - off] : 0;
    __syncthreads();
    tmp[tid] += t;
    __syncthreads();
  }
  if (gid < n) rowptr[gid] = tmp[tid] - v;
  if (tid == 255) partials[blockIdx.x] = tmp[255];
}

__global__ __launch_bounds__(64) void scan_partials_kernel(int* __restrict__ p,
                                                           int n) {
  int lane = threadIdx.x;
  int carry = 0;
  for (int base = 0; base < n; base += 64) {
    int i = base + lane;
    int v = (i < n) ? p[i] : 0;
#pragma unroll
    for (int off = 1; off < 64; off <<= 1) {
      int t = __shfl_up(v, off, 64);
      if (lane >= off) v += t;
    }
    int total = __shfl(v, 63, 64);
    int ex = __shfl_up(v, 1, 64);
    if (lane == 0) ex = 0;
    if (i < n) p[i] = carry + ex;
    carry += total;
  }
}

__global__ __launch_bounds__(256) void add_offsets_kernel(
    int* __restrict__ rowptr, int* __restrict__ cursor,
    const int* __restrict__ partials, int n) {
  int gid = blockIdx.x * 256 + threadIdx.x;
  if (gid < n) {
    int v = rowptr[gid] + partials[blockIdx.x];
    rowptr[gid] = v;
    cursor[gid] = v;
  }
}

__global__ __launch_bounds__(256) void fill_kernel(
    const int* __restrict__ src, const int* __restrict__ dst,
    const float* __restrict__ ew, int* __restrict__ cursor,
    int2* __restrict__ csr, int n) {
  int e = blockIdx.x * 256 + threadIdx.x;
  if (e < n) {
    int d = dst[e];
    int pos = atomicAdd(&cursor[d], 1);
    csr[pos] = make_int2(src[e], __float_as_int(ew[e]));
  }
}

// ---------------------------------------------------------------------------
// Pull aggregation over bf16 H, fp32 accumulate, bf16 out (+bias, +ReLU).
// One wave per dst row, lane = dim.
// ---------------------------------------------------------------------------
template <int D, bool RELU>
__global__ __launch_bounds__(256) void agg_kernel(
    const int* __restrict__ rowptr, const int* __restrict__ deg,
    const int2* __restrict__ csr, const ushort* __restrict__ H,
    const float* __restrict__ b, ushort* __restrict__ out, int nR) {
  int lane = threadIdx.x & 63;
  int r = blockIdx.x * 4 + (threadIdx.x >> 6);
  if (r >= nR) return;
  int beg = rowptr[r];
  int d = deg[r];
  float acc = 0.f;
  for (int j = 0; j < d; ++j) {
    int2 cw = csr[beg + j];
    float w = __int_as_float(cw.y);
    if (D == 64 || lane < D) acc += w * b2f(H[(long)cw.x * D + lane]);
  }
  if (lane < D) {
    float v = acc + b[lane];
    if (RELU) v = fmaxf(v, 0.f);
    out[(long)r * D + lane] = f2b(v);
  }
}

// ---------------------------------------------------------------------------
// Layer-3 fused: aggregation (D=40, bf16 H) + bias + log_softmax, fp32 out.
// ---------------------------------------------------------------------------
__global__ __launch_bounds__(256) void agg_lsm_kernel(
    const int* __restrict__ rowptr, const int* __restrict__ deg,
    const int2* __restrict__ csr, const ushort* __restrict__ H,
    const float* __restrict__ b, float* __restrict__ out, int nR) {
  int lane = threadIdx.x & 63;
  int r = blockIdx.x * 4 + (threadIdx.x >> 6);
  if (r >= nR) return;
  int beg = rowptr[r];
  int d = deg[r];
  float acc = 0.f;
  for (int j = 0; j < d; ++j) {
    int2 cw = csr[beg + j];
    float w = __int_as_float(cw.y);
    if (lane < 40) acc += w * b2f(H[(long)cw.x * 40 + lane]);
  }
  float v = (lane < 40) ? acc + b[lane] : -INFINITY;
  float m = v;
#pragma unroll
  for (int off = 32; off > 0; off >>= 1) m = fmaxf(m, __shfl_xor(m, off, 64));
  float e = (lane < 40) ? __expf(v - m) : 0.f;
  float s = e;
#pragma unroll
  for (int off = 32; off > 0; off >>= 1) s += __shfl_xor(s, off, 64);
  if (lane < 40) out[(long)r * 40 + lane] = v - m - __logf(s);
}

extern "C" void kernel_launch(void* const* d_in, const int* in_sizes, int n_in,
                              void* d_out, int out_size, void* d_ws,
                              size_t ws_size, hipStream_t stream) {
  const int* edge_index = (const int*)d_in[0];
  const float* features = (const float*)d_in[1];
  const float* ew = (const float*)d_in[2];
  const float* W1 = (const float*)d_in[3];
  const float* b1 = (const float*)d_in[4];
  const float* W2 = (const float*)d_in[5];
  const float* b2 = (const float*)d_in[6];
  const float* W3 = (const float*)d_in[7];
  const float* b3 = (const float*)d_in[8];
  float* out = (float*)d_out;
  const int* src = edge_index;
  const int* dst = edge_index + NE;

  // workspace layout
  char* p = (char*)d_ws;
  int2* csr = (int2*)p;              p += (size_t)NE * 8;     // 12.8 MB
  int* deg = (int*)p;                p += (size_t)NN * 4;
  int* rowptr = (int*)p;             p += (size_t)NN * 4;
  int* cursor = (int*)p;             p += (size_t)NN * 4;
  int* partials = (int*)p;           p += 1024 * 4;
  ushort* hb = (ushort*)p;           p += (size_t)NN * 64 * 2;  // GEMM outputs
  ushort* xb = (ushort*)p;           p += (size_t)NN * 64 * 2;  // agg outputs

  dim3 blk(256);
  const int gemm_grid = (NN + 63) / 64;
  const int edge_grid = (NE + 255) / 256;
  const int row_grid = (NN + 3) / 4;

  // ---- CSR build (by dst) ----
  hipMemsetAsync(deg, 0, NN * sizeof(int), stream);
  hist_kernel<<<edge_grid, blk, 0, stream>>>(dst, deg, NE);
  scan_blocks_kernel<<<NB_SCAN, blk, 0, stream>>>(deg, rowptr, partials, NN);
  scan_partials_kernel<<<1, 64, 0, stream>>>(partials, NB_SCAN);
  add_offsets_kernel<<<NB_SCAN, blk, 0, stream>>>(rowptr, cursor, partials, NN);
  fill_kernel<<<edge_grid, blk, 0, stream>>>(src, dst, ew, cursor, csr, NE);

  // ---- layer 1 ----
  mfma_gemm<512, 64, true><<<gemm_grid, blk, 0, stream>>>(features, W1, hb, NN);
  agg_kernel<64, true><<<row_grid, blk, 0, stream>>>(rowptr, deg, csr, hb, b1,
                                                     xb, NN);
  // ---- layer 2 ----
  mfma_gemm<64, 64, false><<<gemm_grid, blk, 0, stream>>>(xb, W2, hb, NN);
  agg_kernel<64, true><<<row_grid, blk, 0, stream>>>(rowptr, deg, csr, hb, b2,
                                                     xb, NN);
  // ---- layer 3 ----
  mfma_gemm<64, 40, false><<<gemm_grid, blk, 0, stream>>>(xb, W3, hb, NN);
  agg_lsm_kernel<<<row_grid, blk, 0, stream>>>(rowptr, deg, csr, hb, b3, out,
                                               NN);
}

// Round 4
// 691.343 us; speedup vs baseline: 2.2719x; 1.4232x over previous
//
#include <hip/hip_runtime.h>
#include <hip/hip_bf16.h>
#include <math.h>

#define NN 100000
#define NE 1600000
#define NB_SCAN ((NN + 255) / 256)  // 391

typedef __attribute__((ext_vector_type(8))) short bf8_t;   // 8 bf16 = 4 VGPRs
typedef __attribute__((ext_vector_type(4))) float f4_t;    // 4 fp32 acc
typedef __attribute__((ext_vector_type(8))) unsigned short us8_t;  // 16B

__device__ __forceinline__ ushort f2b(float f) {
  __hip_bfloat16 h = __float2bfloat16(f);  // RNE
  return *(ushort*)&h;
}
__device__ __forceinline__ float b2f(ushort u) {
  return __uint_as_float(((unsigned)u) << 16);
}

// ---------------------------------------------------------------------------
// bf16 MFMA GEMM: Y[M,N] = X[M,K] @ W[K,N] (bf16 out, fp32 W staged in-kernel)
// ---------------------------------------------------------------------------
template <int K, int N, bool XF32>
__global__ __launch_bounds__(256) void mfma_gemm(
    const void* __restrict__ Xv, const float* __restrict__ Wf,
    ushort* __restrict__ Y, int M) {
  __shared__ ushort xs[64][72];
  __shared__ ushort wsh[64][72];

  const int tid = threadIdx.x;
  const int wave = tid >> 6;
  const int lane = tid & 63;
  const int row0 = blockIdx.x * 64;

  f4_t acc[4];
#pragma unroll
  for (int t = 0; t < 4; t++) acc[t] = (f4_t){0.f, 0.f, 0.f, 0.f};

  for (int k0 = 0; k0 < K; k0 += 64) {
#pragma unroll
    for (int i = 0; i < 4; i++) {
      int fidx = i * 256 + tid;
      int row = fidx >> 4;
      int kq = (fidx & 15) * 4;
      ushort4 uv = make_ushort4(0, 0, 0, 0);
      if (row0 + row < M) {
        if (XF32) {
          const float* Xf = (const float*)Xv;
          float4 xv = *(const float4*)&Xf[(long)(row0 + row) * K + k0 + kq];
          uv = make_ushort4(f2b(xv.x), f2b(xv.y), f2b(xv.z), f2b(xv.w));
        } else {
          const ushort* Xb = (const ushort*)Xv;
          uv = *(const ushort4*)&Xb[(long)(row0 + row) * K + k0 + kq];
        }
      }
      *(ushort4*)&xs[row][kq] = uv;
    }
#pragma unroll
    for (int i = 0; i < 4; i++) {
      int widx = i * 256 + tid;
      int n = widx & 63;
      int kq = (widx >> 6) * 4;
      ushort4 uv = make_ushort4(0, 0, 0, 0);
      if (n < N) {
        uv.x = f2b(Wf[(long)(k0 + kq + 0) * N + n]);
        uv.y = f2b(Wf[(long)(k0 + kq + 1) * N + n]);
        uv.z = f2b(Wf[(long)(k0 + kq + 2) * N + n]);
        uv.w = f2b(Wf[(long)(k0 + kq + 3) * N + n]);
      }
      *(ushort4*)&wsh[n][kq] = uv;
    }
    __syncthreads();
#pragma unroll
    for (int s = 0; s < 2; s++) {
      bf8_t af = *(const bf8_t*)&xs[wave * 16 + (lane & 15)][s * 32 + (lane >> 4) * 8];
#pragma unroll
      for (int t = 0; t < 4; t++) {
        bf8_t bf = *(const bf8_t*)&wsh[t * 16 + (lane & 15)][s * 32 + (lane >> 4) * 8];
        acc[t] = __builtin_amdgcn_mfma_f32_16x16x32_bf16(af, bf, acc[t], 0, 0, 0);
      }
    }
    __syncthreads();
  }
  const int crow0 = row0 + wave * 16 + (lane >> 4) * 4;
  const int ccol = lane & 15;
#pragma unroll
  for (int t = 0; t < 4; t++) {
    int col = ccol + t * 16;
    if (col < N) {
#pragma unroll
      for (int r = 0; r < 4; r++) {
        int row = crow0 + r;
        if (row < M) Y[(long)row * N + col] = f2b(acc[t][r]);
      }
    }
  }
}

// ---------------------------------------------------------------------------
// CSR build: histogram -> 3-phase exclusive scan -> fill (src,w) pairs
// ---------------------------------------------------------------------------
__global__ __launch_bounds__(256) void hist_kernel(const int* __restrict__ dst,
                                                   int* __restrict__ deg, int n) {
  int e = blockIdx.x * 256 + threadIdx.x;
  if (e < n) atomicAdd(&deg[dst[e]], 1);
}

__global__ __launch_bounds__(256) void scan_blocks_kernel(
    const int* __restrict__ deg, int* __restrict__ rowptr,
    int* __restrict__ partials, int n) {
  __shared__ int tmp[256];
  int tid = threadIdx.x;
  int gid = blockIdx.x * 256 + tid;
  int v = (gid < n) ? deg[gid] : 0;
  tmp[tid] = v;
  __syncthreads();
#pragma unroll
  for (int off = 1; off < 256; off <<= 1) {
    int t = (tid >= off) ? tmp[tid - off] : 0;
    __syncthreads();
    tmp[tid] += t;
    __syncthreads();
  }
  if (gid < n) rowptr[gid] = tmp[tid] - v;
  if (tid == 255) partials[blockIdx.x] = tmp[255];
}

__global__ __launch_bounds__(64) void scan_partials_kernel(int* __restrict__ p,
                                                           int n) {
  int lane = threadIdx.x;
  int carry = 0;
  for (int base = 0; base < n; base += 64) {
    int i = base + lane;
    int v = (i < n) ? p[i] : 0;
#pragma unroll
    for (int off = 1; off < 64; off <<= 1) {
      int t = __shfl_up(v, off, 64);
      if (lane >= off) v += t;
    }
    int total = __shfl(v, 63, 64);
    int ex = __shfl_up(v, 1, 64);
    if (lane == 0) ex = 0;
    if (i < n) p[i] = carry + ex;
    carry += total;
  }
}

__global__ __launch_bounds__(256) void add_offsets_kernel(
    int* __restrict__ rowptr, int* __restrict__ cursor,
    const int* __restrict__ partials, int n) {
  int gid = blockIdx.x * 256 + threadIdx.x;
  if (gid < n) {
    int v = rowptr[gid] + partials[blockIdx.x];
    rowptr[gid] = v;
    cursor[gid] = v;
  }
}

__global__ __launch_bounds__(256) void fill_kernel(
    const int* __restrict__ src, const int* __restrict__ dst,
    const float* __restrict__ ew, int* __restrict__ cursor,
    int2* __restrict__ csr, int n) {
  int e = blockIdx.x * 256 + threadIdx.x;
  if (e < n) {
    int d = dst[e];
    int pos = atomicAdd(&cursor[d], 1);
    csr[pos] = make_int2(src[e], __float_as_int(ew[e]));
  }
}

// ---------------------------------------------------------------------------
// Pull aggregation D=64, chunked: 8 edges in flight per wave memory step.
// lane = (g = edge slot [0,8), sub = dim octet [0,8)); 8 dims/lane in regs.
// ---------------------------------------------------------------------------
template <bool RELU>
__global__ __launch_bounds__(256) void agg64_kernel(
    const int* __restrict__ rowptr, const int* __restrict__ deg,
    const int2* __restrict__ csr, const ushort* __restrict__ H,
    const float* __restrict__ b, ushort* __restrict__ out, int nR) {
  int lane = threadIdx.x & 63;
  int r = blockIdx.x * 4 + (threadIdx.x >> 6);
  if (r >= nR) return;
  int beg = rowptr[r];
  int d = deg[r];
  int g = lane >> 3;
  int sub = lane & 7;
  float acc[8];
#pragma unroll
  for (int k = 0; k < 8; k++) acc[k] = 0.f;

  for (int j0 = 0; j0 < d; j0 += 8) {
    int jj = j0 + g;
    int2 cw = (jj < d) ? csr[beg + jj] : make_int2(0, 0);  // w=0 pad
    float w = __int_as_float(cw.y);
    us8_t hv = *(const us8_t*)&H[(long)cw.x * 64 + sub * 8];
#pragma unroll
    for (int k = 0; k < 8; k++) acc[k] += w * b2f(hv[k]);
  }
  // fold the 8 edge slots (lanes differing in bits 3..5)
#pragma unroll
  for (int off = 8; off < 64; off <<= 1)
#pragma unroll
    for (int k = 0; k < 8; k++) acc[k] += __shfl_xor(acc[k], off, 64);

  if (g == 0) {
    us8_t o;
#pragma unroll
    for (int k = 0; k < 8; k++) {
      float v = acc[k] + b[sub * 8 + k];
      if (RELU) v = fmaxf(v, 0.f);
      o[k] = f2b(v);
    }
    *(us8_t*)&out[(long)r * 64 + sub * 8] = o;
  }
}

// ---------------------------------------------------------------------------
// Layer-3 fused: chunked aggregation (D=40) + bias + log_softmax, fp32 out.
// subs 0..4 hold the 40 dims (8 each); subs 5..7 idle on gather.
// ---------------------------------------------------------------------------
__global__ __launch_bounds__(256) void agg_lsm_kernel(
    const int* __restrict__ rowptr, const int* __restrict__ deg,
    const int2* __restrict__ csr, const ushort* __restrict__ H,
    const float* __restrict__ b, float* __restrict__ out, int nR) {
  int lane = threadIdx.x & 63;
  int r = blockIdx.x * 4 + (threadIdx.x >> 6);
  if (r >= nR) return;
  int beg = rowptr[r];
  int d = deg[r];
  int g = lane >> 3;
  int sub = lane & 7;
  float acc[8];
#pragma unroll
  for (int k = 0; k < 8; k++) acc[k] = 0.f;

  for (int j0 = 0; j0 < d; j0 += 8) {
    int jj = j0 + g;
    int2 cw = (jj < d) ? csr[beg + jj] : make_int2(0, 0);
    float w = __int_as_float(cw.y);
    if (sub < 5) {
      us8_t hv = *(const us8_t*)&H[(long)cw.x * 40 + sub * 8];
#pragma unroll
      for (int k = 0; k < 8; k++) acc[k] += w * b2f(hv[k]);
    }
  }
#pragma unroll
  for (int off = 8; off < 64; off <<= 1)
#pragma unroll
    for (int k = 0; k < 8; k++) acc[k] += __shfl_xor(acc[k], off, 64);

  // biased logits for this lane's 8 dims (subs 0..4 valid)
  float v[8];
  float m = -INFINITY, s = 0.f;
  if (sub < 5) {
#pragma unroll
    for (int k = 0; k < 8; k++) {
      v[k] = acc[k] + b[sub * 8 + k];
      m = fmaxf(m, v[k]);
    }
  }
  // row max across subs (bits 0..2)
#pragma unroll
  for (int off = 1; off < 8; off <<= 1) m = fmaxf(m, __shfl_xor(m, off, 64));
  if (sub < 5) {
#pragma unroll
    for (int k = 0; k < 8; k++) s += __expf(v[k] - m);
  }
#pragma unroll
  for (int off = 1; off < 8; off <<= 1) s += __shfl_xor(s, off, 64);

  if (g == 0 && sub < 5) {
    float lg = m + __logf(s);
    float4 o0 = make_float4(v[0] - lg, v[1] - lg, v[2] - lg, v[3] - lg);
    float4 o1 = make_float4(v[4] - lg, v[5] - lg, v[6] - lg, v[7] - lg);
    *(float4*)&out[(long)r * 40 + sub * 8] = o0;
    *(float4*)&out[(long)r * 40 + sub * 8 + 4] = o1;
  }
}

extern "C" void kernel_launch(void* const* d_in, const int* in_sizes, int n_in,
                              void* d_out, int out_size, void* d_ws,
                              size_t ws_size, hipStream_t stream) {
  const int* edge_index = (const int*)d_in[0];
  const float* features = (const float*)d_in[1];
  const float* ew = (const float*)d_in[2];
  const float* W1 = (const float*)d_in[3];
  const float* b1 = (const float*)d_in[4];
  const float* W2 = (const float*)d_in[5];
  const float* b2 = (const float*)d_in[6];
  const float* W3 = (const float*)d_in[7];
  const float* b3 = (const float*)d_in[8];
  float* out = (float*)d_out;
  const int* src = edge_index;
  const int* dst = edge_index + NE;

  // workspace layout (all segment sizes multiples of 128 B)
  char* p = (char*)d_ws;
  int2* csr = (int2*)p;              p += (size_t)NE * 8;
  int* deg = (int*)p;                p += (size_t)NN * 4;
  int* rowptr = (int*)p;             p += (size_t)NN * 4;
  int* cursor = (int*)p;             p += (size_t)NN * 4;
  int* partials = (int*)p;           p += 1024 * 4;
  ushort* hb = (ushort*)p;           p += (size_t)NN * 64 * 2;  // GEMM outputs
  ushort* xb = (ushort*)p;           p += (size_t)NN * 64 * 2;  // agg outputs

  dim3 blk(256);
  const int gemm_grid = (NN + 63) / 64;
  const int edge_grid = (NE + 255) / 256;
  const int row_grid = (NN + 3) / 4;

  // ---- CSR build (by dst) ----
  hipMemsetAsync(deg, 0, NN * sizeof(int), stream);
  hist_kernel<<<edge_grid, blk, 0, stream>>>(dst, deg, NE);
  scan_blocks_kernel<<<NB_SCAN, blk, 0, stream>>>(deg, rowptr, partials, NN);
  scan_partials_kernel<<<1, 64, 0, stream>>>(partials, NB_SCAN);
  add_offsets_kernel<<<NB_SCAN, blk, 0, stream>>>(rowptr, cursor, partials, NN);
  fill_kernel<<<edge_grid, blk, 0, stream>>>(src, dst, ew, cursor, csr, NE);

  // ---- layer 1 ----
  mfma_gemm<512, 64, true><<<gemm_grid, blk, 0, stream>>>(features, W1, hb, NN);
  agg64_kernel<true><<<row_grid, blk, 0, stream>>>(rowptr, deg, csr, hb, b1,
                                                   xb, NN);
  // ---- layer 2 ----
  mfma_gemm<64, 64, false><<<gemm_grid, blk, 0, stream>>>(xb, W2, hb, NN);
  agg64_kernel<true><<<row_grid, blk, 0, stream>>>(rowptr, deg, csr, hb, b2,
                                                   xb, NN);
  // ---- layer 3 ----
  mfma_gemm<64, 40, false><<<gemm_grid, blk, 0, stream>>>(xb, W3, hb, NN);
  agg_lsm_kernel<<<row_grid, blk, 0, stream>>>(rowptr, deg, csr, hb, b3, out,
                                               NN);
}

// Round 5
// 664.906 us; speedup vs baseline: 2.3622x; 1.0398x over previous
//
#include <hip/hip_runtime.h>
#include <hip/hip_bf16.h>
#include <math.h>

#define NN 100000
#define NE 1600000
#define NB_SCAN ((NN + 255) / 256)  // 391
#define NBUK 98                     // dst >> 10, 99999>>10 = 97
#define CHUNK 2048                  // edges per bucket_scatter block

typedef __attribute__((ext_vector_type(8))) short bf8_t;   // 8 bf16 = 4 VGPRs
typedef __attribute__((ext_vector_type(4))) float f4_t;    // 4 fp32 acc
typedef __attribute__((ext_vector_type(8))) unsigned short us8_t;  // 16B

__device__ __forceinline__ ushort f2b(float f) {
  __hip_bfloat16 h = __float2bfloat16(f);  // RNE
  return *(ushort*)&h;
}
__device__ __forceinline__ float b2f(ushort u) {
  return __uint_as_float(((unsigned)u) << 16);
}

// ---------------------------------------------------------------------------
// bf16 MFMA GEMM: Y[M,N] = X[M,K] @ W[K,N] (bf16 out, fp32 W staged in-kernel)
// ---------------------------------------------------------------------------
template <int K, int N, bool XF32>
__global__ __launch_bounds__(256) void mfma_gemm(
    const void* __restrict__ Xv, const float* __restrict__ Wf,
    ushort* __restrict__ Y, int M) {
  __shared__ ushort xs[64][72];
  __shared__ ushort wsh[64][72];

  const int tid = threadIdx.x;
  const int wave = tid >> 6;
  const int lane = tid & 63;
  const int row0 = blockIdx.x * 64;

  f4_t acc[4];
#pragma unroll
  for (int t = 0; t < 4; t++) acc[t] = (f4_t){0.f, 0.f, 0.f, 0.f};

  for (int k0 = 0; k0 < K; k0 += 64) {
#pragma unroll
    for (int i = 0; i < 4; i++) {
      int fidx = i * 256 + tid;
      int row = fidx >> 4;
      int kq = (fidx & 15) * 4;
      ushort4 uv = make_ushort4(0, 0, 0, 0);
      if (row0 + row < M) {
        if (XF32) {
          const float* Xf = (const float*)Xv;
          float4 xv = *(const float4*)&Xf[(long)(row0 + row) * K + k0 + kq];
          uv = make_ushort4(f2b(xv.x), f2b(xv.y), f2b(xv.z), f2b(xv.w));
        } else {
          const ushort* Xb = (const ushort*)Xv;
          uv = *(const ushort4*)&Xb[(long)(row0 + row) * K + k0 + kq];
        }
      }
      *(ushort4*)&xs[row][kq] = uv;
    }
#pragma unroll
    for (int i = 0; i < 4; i++) {
      int widx = i * 256 + tid;
      int n = widx & 63;
      int kq = (widx >> 6) * 4;
      ushort4 uv = make_ushort4(0, 0, 0, 0);
      if (n < N) {
        uv.x = f2b(Wf[(long)(k0 + kq + 0) * N + n]);
        uv.y = f2b(Wf[(long)(k0 + kq + 1) * N + n]);
        uv.z = f2b(Wf[(long)(k0 + kq + 2) * N + n]);
        uv.w = f2b(Wf[(long)(k0 + kq + 3) * N + n]);
      }
      *(ushort4*)&wsh[n][kq] = uv;
    }
    __syncthreads();
#pragma unroll
    for (int s = 0; s < 2; s++) {
      bf8_t af = *(const bf8_t*)&xs[wave * 16 + (lane & 15)][s * 32 + (lane >> 4) * 8];
#pragma unroll
      for (int t = 0; t < 4; t++) {
        bf8_t bf = *(const bf8_t*)&wsh[t * 16 + (lane & 15)][s * 32 + (lane >> 4) * 8];
        acc[t] = __builtin_amdgcn_mfma_f32_16x16x32_bf16(af, bf, acc[t], 0, 0, 0);
      }
    }
    __syncthreads();
  }
  const int crow0 = row0 + wave * 16 + (lane >> 4) * 4;
  const int ccol = lane & 15;
#pragma unroll
  for (int t = 0; t < 4; t++) {
    int col = ccol + t * 16;
    if (col < N) {
#pragma unroll
      for (int r = 0; r < 4; r++) {
        int row = crow0 + r;
        if (row < M) Y[(long)row * N + col] = f2b(acc[t][r]);
      }
    }
  }
}

// ---------------------------------------------------------------------------
// CSR build: histogram -> scan -> bucket scatter -> fine fill
// ---------------------------------------------------------------------------
__global__ __launch_bounds__(256) void hist_kernel(const int* __restrict__ dst,
                                                   int* __restrict__ deg, int n) {
  int e = blockIdx.x * 256 + threadIdx.x;
  if (e < n) atomicAdd(&deg[dst[e]], 1);
}

__global__ __launch_bounds__(256) void scan_blocks_kernel(
    const int* __restrict__ deg, int* __restrict__ rowptr,
    int* __restrict__ partials, int n) {
  __shared__ int tmp[256];
  int tid = threadIdx.x;
  int gid = blockIdx.x * 256 + tid;
  int v = (gid < n) ? deg[gid] : 0;
  tmp[tid] = v;
  __syncthreads();
#pragma unroll
  for (int off = 1; off < 256; off <<= 1) {
    int t = (tid >= off) ? tmp[tid - off] : 0;
    __syncthreads();
    tmp[tid] += t;
    __syncthreads();
  }
  if (gid < n) rowptr[gid] = tmp[tid] - v;
  if (tid == 255) partials[blockIdx.x] = tmp[255];
}

__global__ __launch_bounds__(64) void scan_partials_kernel(int* __restrict__ p,
                                                           int n) {
  int lane = threadIdx.x;
  int carry = 0;
  for (int base = 0; base < n; base += 64) {
    int i = base + lane;
    int v = (i < n) ? p[i] : 0;
#pragma unroll
    for (int off = 1; off < 64; off <<= 1) {
      int t = __shfl_up(v, off, 64);
      if (lane >= off) v += t;
    }
    int total = __shfl(v, 63, 64);
    int ex = __shfl_up(v, 1, 64);
    if (lane == 0) ex = 0;
    if (i < n) p[i] = carry + ex;
    carry += total;
  }
}

__global__ __launch_bounds__(256) void add_offsets_kernel(
    int* __restrict__ rowptr, int* __restrict__ cursor,
    const int* __restrict__ partials, int n) {
  int gid = blockIdx.x * 256 + threadIdx.x;
  if (gid < n) {
    int v = rowptr[gid] + partials[blockIdx.x];
    rowptr[gid] = v;
    cursor[gid] = v;
  }
}

// bucket cursors start at the bucket's CSR extent (rowptr at boundary node)
__global__ __launch_bounds__(128) void bcur_init_kernel(
    const int* __restrict__ rowptr, int* __restrict__ bcur) {
  int b = threadIdx.x;
  if (b < NBUK) bcur[b] = rowptr[b << 10];
}

// Pass B: group edges by bucket (dst>>10) with block-aggregated reservation.
// Writes are contiguous runs per (block,bucket) -> ~1x write amplification.
__global__ __launch_bounds__(256) void bucket_scatter_kernel(
    const int* __restrict__ src, const int* __restrict__ dst,
    const float* __restrict__ ew, int* __restrict__ bcur,
    int2* __restrict__ esw, int* __restrict__ ed, int n) {
  __shared__ int lcnt[NBUK];
  __shared__ int lbase[NBUK];
  const int tid = threadIdx.x;
  const int e0 = blockIdx.x * CHUNK;
  for (int i = tid; i < NBUK; i += 256) lcnt[i] = 0;
  __syncthreads();

  int es[8], ds[8], rk[8];
  float wv[8];
#pragma unroll
  for (int k = 0; k < 8; k++) {
    int e = e0 + k * 256 + tid;
    if (e < n) {
      es[k] = src[e];
      ds[k] = dst[e];
      wv[k] = ew[e];
      rk[k] = atomicAdd(&lcnt[ds[k] >> 10], 1);
    } else {
      ds[k] = -1;
    }
  }
  __syncthreads();
  for (int i = tid; i < NBUK; i += 256)
    lbase[i] = lcnt[i] ? atomicAdd(&bcur[i], lcnt[i]) : 0;
  __syncthreads();
#pragma unroll
  for (int k = 0; k < 8; k++) {
    if (ds[k] >= 0) {
      int p = lbase[ds[k] >> 10] + rk[k];
      esw[p] = make_int2(es[k], __float_as_int(wv[k]));
      ed[p] = ds[k];
    }
  }
}

// Pass C: edges now bucket-grouped; per-node scatter stays inside one
// bucket's <=132KB CSR window -> L2-absorbed writes.
__global__ __launch_bounds__(256) void fine_fill_kernel(
    const int2* __restrict__ esw, const int* __restrict__ ed,
    int* __restrict__ cursor, int2* __restrict__ csr, int n) {
  int i = blockIdx.x * 256 + threadIdx.x;
  if (i < n) {
    int d = ed[i];
    int pos = atomicAdd(&cursor[d], 1);
    csr[pos] = esw[i];
  }
}

// ---------------------------------------------------------------------------
// Pull aggregation D=64, chunked: 8 edges in flight per wave memory step.
// ---------------------------------------------------------------------------
template <bool RELU>
__global__ __launch_bounds__(256) void agg64_kernel(
    const int* __restrict__ rowptr, const int* __restrict__ deg,
    const int2* __restrict__ csr, const ushort* __restrict__ H,
    const float* __restrict__ b, ushort* __restrict__ out, int nR) {
  int lane = threadIdx.x & 63;
  int r = blockIdx.x * 4 + (threadIdx.x >> 6);
  if (r >= nR) return;
  int beg = rowptr[r];
  int d = deg[r];
  int g = lane >> 3;
  int sub = lane & 7;
  float acc[8];
#pragma unroll
  for (int k = 0; k < 8; k++) acc[k] = 0.f;

  for (int j0 = 0; j0 < d; j0 += 8) {
    int jj = j0 + g;
    int2 cw = (jj < d) ? csr[beg + jj] : make_int2(0, 0);  // w=0 pad
    float w = __int_as_float(cw.y);
    us8_t hv = *(const us8_t*)&H[(long)cw.x * 64 + sub * 8];
#pragma unroll
    for (int k = 0; k < 8; k++) acc[k] += w * b2f(hv[k]);
  }
#pragma unroll
  for (int off = 8; off < 64; off <<= 1)
#pragma unroll
    for (int k = 0; k < 8; k++) acc[k] += __shfl_xor(acc[k], off, 64);

  if (g == 0) {
    us8_t o;
#pragma unroll
    for (int k = 0; k < 8; k++) {
      float v = acc[k] + b[sub * 8 + k];
      if (RELU) v = fmaxf(v, 0.f);
      o[k] = f2b(v);
    }
    *(us8_t*)&out[(long)r * 64 + sub * 8] = o;
  }
}

// ---------------------------------------------------------------------------
// Layer-3 fused: chunked aggregation (D=40) + bias + log_softmax, fp32 out.
// ---------------------------------------------------------------------------
__global__ __launch_bounds__(256) void agg_lsm_kernel(
    const int* __restrict__ rowptr, const int* __restrict__ deg,
    const int2* __restrict__ csr, const ushort* __restrict__ H,
    const float* __restrict__ b, float* __restrict__ out, int nR) {
  int lane = threadIdx.x & 63;
  int r = blockIdx.x * 4 + (threadIdx.x >> 6);
  if (r >= nR) return;
  int beg = rowptr[r];
  int d = deg[r];
  int g = lane >> 3;
  int sub = lane & 7;
  float acc[8];
#pragma unroll
  for (int k = 0; k < 8; k++) acc[k] = 0.f;

  for (int j0 = 0; j0 < d; j0 += 8) {
    int jj = j0 + g;
    int2 cw = (jj < d) ? csr[beg + jj] : make_int2(0, 0);
    float w = __int_as_float(cw.y);
    if (sub < 5) {
      us8_t hv = *(const us8_t*)&H[(long)cw.x * 40 + sub * 8];
#pragma unroll
      for (int k = 0; k < 8; k++) acc[k] += w * b2f(hv[k]);
    }
  }
#pragma unroll
  for (int off = 8; off < 64; off <<= 1)
#pragma unroll
    for (int k = 0; k < 8; k++) acc[k] += __shfl_xor(acc[k], off, 64);

  float v[8];
  float m = -INFINITY, s = 0.f;
  if (sub < 5) {
#pragma unroll
    for (int k = 0; k < 8; k++) {
      v[k] = acc[k] + b[sub * 8 + k];
      m = fmaxf(m, v[k]);
    }
  }
#pragma unroll
  for (int off = 1; off < 8; off <<= 1) m = fmaxf(m, __shfl_xor(m, off, 64));
  if (sub < 5) {
#pragma unroll
    for (int k = 0; k < 8; k++) s += __expf(v[k] - m);
  }
#pragma unroll
  for (int off = 1; off < 8; off <<= 1) s += __shfl_xor(s, off, 64);

  if (g == 0 && sub < 5) {
    float lg = m + __logf(s);
    float4 o0 = make_float4(v[0] - lg, v[1] - lg, v[2] - lg, v[3] - lg);
    float4 o1 = make_float4(v[4] - lg, v[5] - lg, v[6] - lg, v[7] - lg);
    *(float4*)&out[(long)r * 40 + sub * 8] = o0;
    *(float4*)&out[(long)r * 40 + sub * 8 + 4] = o1;
  }
}

extern "C" void kernel_launch(void* const* d_in, const int* in_sizes, int n_in,
                              void* d_out, int out_size, void* d_ws,
                              size_t ws_size, hipStream_t stream) {
  const int* edge_index = (const int*)d_in[0];
  const float* features = (const float*)d_in[1];
  const float* ew = (const float*)d_in[2];
  const float* W1 = (const float*)d_in[3];
  const float* b1 = (const float*)d_in[4];
  const float* W2 = (const float*)d_in[5];
  const float* b2 = (const float*)d_in[6];
  const float* W3 = (const float*)d_in[7];
  const float* b3 = (const float*)d_in[8];
  float* out = (float*)d_out;
  const int* src = edge_index;
  const int* dst = edge_index + NE;

  // workspace layout
  char* p = (char*)d_ws;
  int2* csr = (int2*)p;              p += (size_t)NE * 8;
  int* deg = (int*)p;                p += (size_t)NN * 4;
  int* rowptr = (int*)p;             p += (size_t)NN * 4;
  int* cursor = (int*)p;             p += (size_t)NN * 4;
  int* partials = (int*)p;           p += 1024 * 4;
  int* bcur = (int*)p;               p += 128 * 4;
  ushort* hb = (ushort*)p;           p += (size_t)NN * 64 * 2;  // GEMM outputs
  ushort* xb = (ushort*)p;           p += (size_t)NN * 64 * 2;  // agg outputs
  // CSR build fully precedes layer compute -> alias edge staging onto hb/xb
  int2* esw = (int2*)hb;             // NE * 8B = 12.8 MB (== hb size)
  int* ed = (int*)xb;                // NE * 4B = 6.4 MB

  dim3 blk(256);
  const int gemm_grid = (NN + 63) / 64;
  const int edge_grid = (NE + 255) / 256;
  const int row_grid = (NN + 3) / 4;

  // ---- CSR build (by dst) ----
  hipMemsetAsync(deg, 0, NN * sizeof(int), stream);
  hist_kernel<<<edge_grid, blk, 0, stream>>>(dst, deg, NE);
  scan_blocks_kernel<<<NB_SCAN, blk, 0, stream>>>(deg, rowptr, partials, NN);
  scan_partials_kernel<<<1, 64, 0, stream>>>(partials, NB_SCAN);
  add_offsets_kernel<<<NB_SCAN, blk, 0, stream>>>(rowptr, cursor, partials, NN);
  bcur_init_kernel<<<1, 128, 0, stream>>>(rowptr, bcur);
  bucket_scatter_kernel<<<(NE + CHUNK - 1) / CHUNK, blk, 0, stream>>>(
      src, dst, ew, bcur, esw, ed, NE);
  fine_fill_kernel<<<edge_grid, blk, 0, stream>>>(esw, ed, cursor, csr, NE);

  // ---- layer 1 ----
  mfma_gemm<512, 64, true><<<gemm_grid, blk, 0, stream>>>(features, W1, hb, NN);
  agg64_kernel<true><<<row_grid, blk, 0, stream>>>(rowptr, deg, csr, hb, b1,
                                                   xb, NN);
  // ---- layer 2 ----
  mfma_gemm<64, 64, false><<<gemm_grid, blk, 0, stream>>>(xb, W2, hb, NN);
  agg64_kernel<true><<<row_grid, blk, 0, stream>>>(rowptr, deg, csr, hb, b2,
                                                   xb, NN);
  // ---- layer 3 ----
  mfma_gemm<64, 40, false><<<gemm_grid, blk, 0, stream>>>(xb, W3, hb, NN);
  agg_lsm_kernel<<<row_grid, blk, 0, stream>>>(rowptr, deg, csr, hb, b3, out,
                                               NN);
}